// Round 1
// 1407.704 us; speedup vs baseline: 1.2390x; 1.2390x over previous
//
#include <hip/hip_runtime.h>

#define D 64
#define SCAN_BS 1024

// ---------------- CSR build ----------------

__global__ void count_deg_kernel(const int* __restrict__ dst, int* __restrict__ counts, int nnz) {
    int e = blockIdx.x * blockDim.x + threadIdx.x;
    if (e < nnz) atomicAdd(&counts[dst[e]], 1);
}

__global__ void scan_blocks_kernel(const int* __restrict__ counts, int* __restrict__ offs,
                                   int* __restrict__ partials, int n) {
    __shared__ int sh[SCAN_BS];
    int tid = threadIdx.x;
    int i = blockIdx.x * SCAN_BS + tid;
    int v = (i < n) ? counts[i] : 0;
    sh[tid] = v;
    __syncthreads();
    for (int ofs = 1; ofs < SCAN_BS; ofs <<= 1) {
        int t = (tid >= ofs) ? sh[tid - ofs] : 0;
        __syncthreads();
        sh[tid] += t;
        __syncthreads();
    }
    if (i < n) offs[i] = sh[tid] - v;  // exclusive within block
    if (tid == SCAN_BS - 1) partials[blockIdx.x] = sh[tid];
}

__global__ void scan_partials_kernel(int* partials, int nb) {
    __shared__ int sh[SCAN_BS];
    int tid = threadIdx.x;
    int v = (tid < nb) ? partials[tid] : 0;
    sh[tid] = v;
    __syncthreads();
    for (int ofs = 1; ofs < SCAN_BS; ofs <<= 1) {
        int t = (tid >= ofs) ? sh[tid - ofs] : 0;
        __syncthreads();
        sh[tid] += t;
        __syncthreads();
    }
    if (tid < nb) partials[tid] = sh[tid] - v;  // exclusive
}

__global__ void add_base_kernel(int* __restrict__ offs, const int* __restrict__ partials,
                                int n, int nnz) {
    int i = blockIdx.x * SCAN_BS + threadIdx.x;
    if (i < n) offs[i] += partials[blockIdx.x];
    if (blockIdx.x == 0 && threadIdx.x == 0) offs[n] = nnz;
}

// fill: 8 dst-range groups keyed by blockIdx&7 (XCD round-robin heuristic).
// Each group's CSR region is ~4 MB -> single-L2 resident -> scattered 8B
// stores to the same 64B line actually merge before writeback.
// Edge re-reads (8x) are L3-resident; nontemporal so they don't evict the
// dirty CSR lines.
__global__ __launch_bounds__(256) void fill_csr_kernel(
        const int* __restrict__ src, const int* __restrict__ dst,
        const float* __restrict__ val, int* __restrict__ cursor,
        int2* __restrict__ csr, int nnz, int n_nodes) {
    int grp = blockIdx.x & 7;
    int blk = blockIdx.x >> 3;                    // 0..(nblk_per_grp-1)
    int nblk = (int)(gridDim.x >> 3);
    int lo = (int)(((long long)n_nodes * grp) >> 3);
    int hi = (int)(((long long)n_nodes * (grp + 1)) >> 3);
    int per = (nnz + nblk - 1) / nblk;            // edges per block
    int e_beg = blk * per;
    int e_end = min(nnz, e_beg + per);
    for (int e = e_beg + (int)threadIdx.x; e < e_end; e += 256) {
        int d = __builtin_nontemporal_load(&dst[e]);
        if (d >= lo && d < hi) {
            int p = atomicAdd(&cursor[d], 1);
            int2 pk = make_int2(__float_as_int(__builtin_nontemporal_load(&val[e])),
                                __builtin_nontemporal_load(&src[e]));
            csr[p] = pk;   // one 8B scattered store instead of two 4B
        }
    }
}

// ---------------- SpMM: one wave per dst node ----------------
// 4 lane-groups of 16; group g handles edge j+g via float4 row reads
// (4 edges in flight per inner step), cross-group shfl_xor reduce at end.

template <bool FIRST, bool LAST>
__global__ __launch_bounds__(256) void spmm_kernel(
        const int* __restrict__ offs, const int2* __restrict__ csr,
        const float* __restrict__ x_in,
        const float* __restrict__ user_emb, const float* __restrict__ item_emb,
        float* __restrict__ x_out, float* __restrict__ acc,
        int n_nodes, int n_users) {
    int wave = (int)((blockIdx.x * blockDim.x + threadIdx.x) >> 6);
    if (wave >= n_nodes) return;
    int lane = threadIdx.x & 63;
    int g = lane >> 4;        // edge sub-group 0..3
    int sl = lane & 15;       // feature-quad index
    int e0 = offs[wave], e1 = offs[wave + 1];
    float4 s4 = make_float4(0.f, 0.f, 0.f, 0.f);
    for (int base = e0; base < e1; base += 64) {
        int e = base + lane;
        int2 pe = make_int2(0, 0);                // val=0.0f, src=0 for OOB lanes
        if (e < e1) pe = csr[e];                  // coalesced 8B chunk load
        int cnt = min(64, e1 - base);
        for (int j = 0; j < cnt; j += 4) {
            int jj = j + g;                       // jj <= 63 always
            float vj = __shfl(__int_as_float(pe.x), jj);  // 0.0 when jj >= cnt
            int sj = __shfl(pe.y, jj);
            const float* rp;
            if (FIRST)
                rp = (sj < n_users) ? (user_emb + (size_t)sj * D)
                                    : (item_emb + (size_t)(sj - n_users) * D);
            else
                rp = x_in + (size_t)sj * D;
            float4 r = ((const float4*)rp)[sl];   // 16 lanes x 16B = full 256B row
            s4.x = fmaf(vj, r.x, s4.x);
            s4.y = fmaf(vj, r.y, s4.y);
            s4.z = fmaf(vj, r.z, s4.z);
            s4.w = fmaf(vj, r.w, s4.w);
        }
    }
    // reduce the 4 edge-groups: lanes {sl, sl+16, sl+32, sl+48} hold partials
    s4.x += __shfl_xor(s4.x, 16); s4.x += __shfl_xor(s4.x, 32);
    s4.y += __shfl_xor(s4.y, 16); s4.y += __shfl_xor(s4.y, 32);
    s4.z += __shfl_xor(s4.z, 16); s4.z += __shfl_xor(s4.z, 32);
    s4.w += __shfl_xor(s4.w, 16); s4.w += __shfl_xor(s4.w, 32);
    if (lane < 16) {
        size_t oi = (size_t)wave * D + (size_t)sl * 4;
        float4 a = *(const float4*)(acc + oi);
        a.x += s4.x; a.y += s4.y; a.z += s4.z; a.w += s4.w;
        *(float4*)(acc + oi) = a;
        if (!LAST) *(float4*)(x_out + oi) = s4;   // layer-3 x_out is dead: skip
    }
}

// ---------------- Rating GEMM: (batch x 64) * (64 x n_items), fp32 ----------------

#define BM 128
#define BN 128
#define TM 8
#define TN 8
#define KB 32
#define PAD 4

__global__ __launch_bounds__(256) void rating_gemm_kernel(
        const float* __restrict__ acc, const int* __restrict__ users,
        float* __restrict__ out, int n_users, int n_items, int batch) {
    __shared__ __align__(16) float As[KB][BM + PAD];
    __shared__ __align__(16) float Bs[KB][BN + PAD];
    int m0 = blockIdx.y * BM;
    int n0 = blockIdx.x * BN;
    int tid = threadIdx.x;
    int tx = tid & 15, ty = tid >> 4;
    float c[TM][TN] = {};

    for (int k0 = 0; k0 < D; k0 += KB) {
        for (int f = tid; f < BM * (KB / 4); f += 256) {
            int m = f >> 3;
            int k4 = (f & 7) * 4;
            float4 a = make_float4(0.f, 0.f, 0.f, 0.f);
            int gm = m0 + m;
            if (gm < batch) {
                int uid = users[gm];
                a = *(const float4*)(acc + (size_t)uid * D + k0 + k4);
            }
            As[k4 + 0][m] = a.x; As[k4 + 1][m] = a.y;
            As[k4 + 2][m] = a.z; As[k4 + 3][m] = a.w;
        }
        for (int f = tid; f < BN * (KB / 4); f += 256) {
            int n = f >> 3;
            int k4 = (f & 7) * 4;
            float4 b = make_float4(0.f, 0.f, 0.f, 0.f);
            int gi = n0 + n;
            if (gi < n_items) {
                b = *(const float4*)(acc + (size_t)(n_users + gi) * D + k0 + k4);
            }
            Bs[k4 + 0][n] = b.x; Bs[k4 + 1][n] = b.y;
            Bs[k4 + 2][n] = b.z; Bs[k4 + 3][n] = b.w;
        }
        __syncthreads();
        #pragma unroll
        for (int k = 0; k < KB; ++k) {
            float a[TM], b[TN];
            float4 t;
            t = *(const float4*)&As[k][ty * TM];     a[0] = t.x; a[1] = t.y; a[2] = t.z; a[3] = t.w;
            t = *(const float4*)&As[k][ty * TM + 4]; a[4] = t.x; a[5] = t.y; a[6] = t.z; a[7] = t.w;
            t = *(const float4*)&Bs[k][tx * TN];     b[0] = t.x; b[1] = t.y; b[2] = t.z; b[3] = t.w;
            t = *(const float4*)&Bs[k][tx * TN + 4]; b[4] = t.x; b[5] = t.y; b[6] = t.z; b[7] = t.w;
            #pragma unroll
            for (int i = 0; i < TM; ++i)
                #pragma unroll
                for (int j = 0; j < TN; ++j)
                    c[i][j] = fmaf(a[i], b[j], c[i][j]);
        }
        __syncthreads();
    }

    const float S = 1.0f / 16.0f;  // (acc/4)·(acc/4)
    for (int i = 0; i < TM; ++i) {
        int m = m0 + ty * TM + i;
        if (m >= batch) break;
        float* row = out + (size_t)m * n_items;
        for (int j = 0; j < TN; j += 4) {
            int n = n0 + tx * TN + j;
            if (n + 4 <= n_items) {
                float4 v;
                v.x = c[i][j + 0] * S; v.y = c[i][j + 1] * S;
                v.z = c[i][j + 2] * S; v.w = c[i][j + 3] * S;
                *(float4*)(row + n) = v;
            } else {
                for (int u = 0; u < 4; ++u)
                    if (n + u < n_items) row[n + u] = c[i][j + u] * S;
            }
        }
    }
}

// ---------------- launcher ----------------

extern "C" void kernel_launch(void* const* d_in, const int* in_sizes, int n_in,
                              void* d_out, int out_size, void* d_ws, size_t ws_size,
                              hipStream_t stream) {
    const float* user_emb = (const float*)d_in[0];
    const float* item_emb = (const float*)d_in[1];
    const float* edge_val = (const float*)d_in[2];
    const int*   edge_src = (const int*)d_in[3];
    const int*   edge_dst = (const int*)d_in[4];
    const int*   users    = (const int*)d_in[5];

    const int n_users = in_sizes[0] / D;   // 100000
    const int n_items = in_sizes[1] / D;   // 50000
    const int nnz     = in_sizes[2];       // 4000000
    const int batch   = in_sizes[5];       // 2048
    const int n_nodes = n_users + n_items; // 150000

    // workspace carve-out (~148 MB)
    char* w = (char*)d_ws;
    size_t off = 0;
    auto alloc = [&](size_t bytes) -> void* {
        void* p = w + off;
        off += (bytes + 255) & ~(size_t)255;
        return p;
    };
    float* acc      = (float*)alloc((size_t)n_nodes * D * 4);
    float* xA       = (float*)alloc((size_t)n_nodes * D * 4);
    float* xB       = (float*)alloc((size_t)n_nodes * D * 4);
    int*   counts   = (int*)alloc((size_t)n_nodes * 4);
    int*   offs     = (int*)alloc((size_t)(n_nodes + 1) * 4);
    int*   partials = (int*)alloc((size_t)SCAN_BS * 4);
    int*   cursor   = (int*)alloc((size_t)n_nodes * 4);
    int2*  csr      = (int2*)alloc((size_t)nnz * 8);
    (void)ws_size; (void)n_in; (void)out_size;

    // acc = concat(user_emb, item_emb)
    hipMemcpyAsync(acc, user_emb, (size_t)n_users * D * 4, hipMemcpyDeviceToDevice, stream);
    hipMemcpyAsync(acc + (size_t)n_users * D, item_emb, (size_t)n_items * D * 4,
                   hipMemcpyDeviceToDevice, stream);

    // CSR by dst
    hipMemsetAsync(counts, 0, (size_t)n_nodes * 4, stream);
    count_deg_kernel<<<(nnz + 255) / 256, 256, 0, stream>>>(edge_dst, counts, nnz);
    int nb = (n_nodes + SCAN_BS - 1) / SCAN_BS;
    scan_blocks_kernel<<<nb, SCAN_BS, 0, stream>>>(counts, offs, partials, n_nodes);
    scan_partials_kernel<<<1, SCAN_BS, 0, stream>>>(partials, nb);
    add_base_kernel<<<nb, SCAN_BS, 0, stream>>>(offs, partials, n_nodes, nnz);
    hipMemcpyAsync(cursor, offs, (size_t)n_nodes * 4, hipMemcpyDeviceToDevice, stream);
    // 8 groups x 256 blocks = 2048 blocks (fills 256 CUs at 4 waves/block)
    fill_csr_kernel<<<2048, 256, 0, stream>>>(edge_src, edge_dst, edge_val,
                                              cursor, csr, nnz, n_nodes);

    // 3 SpMM layers, acc += each
    int spmm_blocks = (n_nodes + 3) / 4;  // 4 waves per 256-thread block
    spmm_kernel<true, false><<<spmm_blocks, 256, 0, stream>>>(
        offs, csr, nullptr, user_emb, item_emb, xA, acc, n_nodes, n_users);
    spmm_kernel<false, false><<<spmm_blocks, 256, 0, stream>>>(
        offs, csr, xA, nullptr, nullptr, xB, acc, n_nodes, n_users);
    spmm_kernel<false, true><<<spmm_blocks, 256, 0, stream>>>(
        offs, csr, xB, nullptr, nullptr, xA /*unused*/, acc, n_nodes, n_users);

    // rating = users_emb @ items^T / 16
    dim3 ggrid((n_items + BN - 1) / BN, (batch + BM - 1) / BM);
    rating_gemm_kernel<<<ggrid, 256, 0, stream>>>(acc, users, (float*)d_out,
                                                  n_users, n_items, batch);
}

// Round 3
// 1387.068 us; speedup vs baseline: 1.2574x; 1.0149x over previous
//
#include <hip/hip_runtime.h>

#define D 64
#define SCAN_BS 1024

// ---------------- CSR build ----------------

__global__ void count_deg_kernel(const int* __restrict__ dst, int* __restrict__ counts, int nnz) {
    int e = blockIdx.x * blockDim.x + threadIdx.x;
    if (e < nnz) atomicAdd(&counts[dst[e]], 1);
}

__global__ void scan_blocks_kernel(const int* __restrict__ counts, int* __restrict__ offs,
                                   int* __restrict__ partials, int n) {
    __shared__ int sh[SCAN_BS];
    int tid = threadIdx.x;
    int i = blockIdx.x * SCAN_BS + tid;
    int v = (i < n) ? counts[i] : 0;
    sh[tid] = v;
    __syncthreads();
    for (int ofs = 1; ofs < SCAN_BS; ofs <<= 1) {
        int t = (tid >= ofs) ? sh[tid - ofs] : 0;
        __syncthreads();
        sh[tid] += t;
        __syncthreads();
    }
    if (i < n) offs[i] = sh[tid] - v;  // exclusive within block
    if (tid == SCAN_BS - 1) partials[blockIdx.x] = sh[tid];
}

__global__ void scan_partials_kernel(int* partials, int nb) {
    __shared__ int sh[SCAN_BS];
    int tid = threadIdx.x;
    int v = (tid < nb) ? partials[tid] : 0;
    sh[tid] = v;
    __syncthreads();
    for (int ofs = 1; ofs < SCAN_BS; ofs <<= 1) {
        int t = (tid >= ofs) ? sh[tid - ofs] : 0;
        __syncthreads();
        sh[tid] += t;
        __syncthreads();
    }
    if (tid < nb) partials[tid] = sh[tid] - v;  // exclusive
}

__global__ void add_base_kernel(int* __restrict__ offs, const int* __restrict__ partials,
                                int n, int nnz) {
    int i = blockIdx.x * SCAN_BS + threadIdx.x;
    if (i < n) offs[i] += partials[blockIdx.x];
    if (blockIdx.x == 0 && threadIdx.x == 0) offs[n] = nnz;
}

// fill: 8 dst-range groups keyed by blockIdx&7 (XCD round-robin heuristic).
// Each group's CSR region is ~4 MB -> single-L2 resident -> scattered 8B
// stores to the same 64B line merge before writeback.
__global__ __launch_bounds__(256) void fill_csr_kernel(
        const int* __restrict__ src, const int* __restrict__ dst,
        const float* __restrict__ val, int* __restrict__ cursor,
        int2* __restrict__ csr, int nnz, int n_nodes) {
    int grp = blockIdx.x & 7;
    int blk = blockIdx.x >> 3;
    int nblk = (int)(gridDim.x >> 3);
    int lo = (int)(((long long)n_nodes * grp) >> 3);
    int hi = (int)(((long long)n_nodes * (grp + 1)) >> 3);
    int per = (nnz + nblk - 1) / nblk;
    int e_beg = blk * per;
    int e_end = min(nnz, e_beg + per);
    for (int e = e_beg + (int)threadIdx.x; e < e_end; e += 256) {
        int d = __builtin_nontemporal_load(&dst[e]);
        if (d >= lo && d < hi) {
            int p = atomicAdd(&cursor[d], 1);
            int2 pk = make_int2(__float_as_int(__builtin_nontemporal_load(&val[e])),
                                __builtin_nontemporal_load(&src[e]));
            csr[p] = pk;
        }
    }
}

// ---------------- SpMM: one wave per dst node ----------------
// 8 lane-groups of 8; group g handles edge j+g via 2x float4 row reads
// (8 edges / 16 gathers per trip), 2-stage software pipeline across trips,
// 3-step shfl_xor cross-group reduce at the end.
// LAST layer fuses acc finalize: acc = emb + x1 + x2 + spmm_sum.

template <bool FIRST, bool LAST>
__global__ __launch_bounds__(256) void spmm_kernel(
        const int* __restrict__ offs, const int2* __restrict__ csr,
        const float* __restrict__ x_in,
        const float* __restrict__ user_emb, const float* __restrict__ item_emb,
        const float* __restrict__ xp0, const float* __restrict__ xp1,
        float* __restrict__ x_out,
        int n_nodes, int n_users) {
    int wave = (int)((blockIdx.x * blockDim.x + threadIdx.x) >> 6);
    if (wave >= n_nodes) return;
    int lane = threadIdx.x & 63;
    int g = lane >> 3;       // edge sub-group 0..7
    int sl = lane & 7;       // feature-octet index (floats [sl*8, sl*8+8))
    int e0 = offs[wave], e1 = offs[wave + 1];
    float4 a0 = make_float4(0.f, 0.f, 0.f, 0.f);
    float4 a1 = make_float4(0.f, 0.f, 0.f, 0.f);

    for (int base = e0; base < e1; base += 64) {
        int e = base + lane;
        int2 pe = make_int2(0, 0);               // val=0.0f, src=0 for OOB lanes
        if (e < e1) pe = csr[e];                 // coalesced 512B chunk load
        int cnt = min(64, e1 - base);
        float pv = __int_as_float(pe.x);
        int   ps = pe.y;

        // prologue: issue loads for trip j=0
        float vc; float4 c0, c1;
        {
            int jj = g;                          // <= 7
            vc = __shfl(pv, jj);                 // 0.0 when jj >= cnt -> FMA no-op
            int sj = __shfl(ps, jj);             // 0 when jj >= cnt -> safe addr
            const float* rp;
            if (FIRST)
                rp = (sj < n_users) ? (user_emb + (size_t)sj * D)
                                    : (item_emb + (size_t)(sj - n_users) * D);
            else
                rp = x_in + (size_t)sj * D;
            const float4* rq = (const float4*)rp;
            c0 = rq[sl * 2];
            c1 = rq[sl * 2 + 1];
        }
        for (int j = 0; j < cnt; j += 8) {
            float vn = 0.f;
            float4 n0 = make_float4(0.f, 0.f, 0.f, 0.f);
            float4 n1 = make_float4(0.f, 0.f, 0.f, 0.f);
            if (j + 8 < cnt) {                   // wave-uniform; jj <= 63 guaranteed
                int jj = j + 8 + g;
                vn = __shfl(pv, jj);
                int sj = __shfl(ps, jj);
                const float* rp;
                if (FIRST)
                    rp = (sj < n_users) ? (user_emb + (size_t)sj * D)
                                        : (item_emb + (size_t)(sj - n_users) * D);
                else
                    rp = x_in + (size_t)sj * D;
                const float4* rq = (const float4*)rp;
                n0 = rq[sl * 2];                 // issued before current FMAs ->
                n1 = rq[sl * 2 + 1];             // up to 4 gathers in flight
            }
            a0.x = fmaf(vc, c0.x, a0.x);
            a0.y = fmaf(vc, c0.y, a0.y);
            a0.z = fmaf(vc, c0.z, a0.z);
            a0.w = fmaf(vc, c0.w, a0.w);
            a1.x = fmaf(vc, c1.x, a1.x);
            a1.y = fmaf(vc, c1.y, a1.y);
            a1.z = fmaf(vc, c1.z, a1.z);
            a1.w = fmaf(vc, c1.w, a1.w);
            vc = vn; c0 = n0; c1 = n1;
        }
    }

    // reduce the 8 edge-groups: lanes {g*8+sl} -> xor over g bits (8,16,32)
    a0.x += __shfl_xor(a0.x, 8);  a0.x += __shfl_xor(a0.x, 16); a0.x += __shfl_xor(a0.x, 32);
    a0.y += __shfl_xor(a0.y, 8);  a0.y += __shfl_xor(a0.y, 16); a0.y += __shfl_xor(a0.y, 32);
    a0.z += __shfl_xor(a0.z, 8);  a0.z += __shfl_xor(a0.z, 16); a0.z += __shfl_xor(a0.z, 32);
    a0.w += __shfl_xor(a0.w, 8);  a0.w += __shfl_xor(a0.w, 16); a0.w += __shfl_xor(a0.w, 32);
    a1.x += __shfl_xor(a1.x, 8);  a1.x += __shfl_xor(a1.x, 16); a1.x += __shfl_xor(a1.x, 32);
    a1.y += __shfl_xor(a1.y, 8);  a1.y += __shfl_xor(a1.y, 16); a1.y += __shfl_xor(a1.y, 32);
    a1.z += __shfl_xor(a1.z, 8);  a1.z += __shfl_xor(a1.z, 16); a1.z += __shfl_xor(a1.z, 32);
    a1.w += __shfl_xor(a1.w, 8);  a1.w += __shfl_xor(a1.w, 16); a1.w += __shfl_xor(a1.w, 32);

    if (lane < 8) {
        size_t oi = (size_t)wave * D + (size_t)sl * 8;
        if (LAST) {
            // acc = x0(own emb) + x1 + x2 + spmm_sum   (all coalesced own-row reads)
            const float* ep = (wave < n_users) ? (user_emb + (size_t)wave * D)
                                               : (item_emb + (size_t)(wave - n_users) * D);
            float4 z0 = ((const float4*)ep)[sl * 2];
            float4 z1 = ((const float4*)ep)[sl * 2 + 1];
            float4 y0 = *(const float4*)(xp0 + oi);
            float4 y1 = *(const float4*)(xp0 + oi + 4);
            float4 w0 = *(const float4*)(xp1 + oi);
            float4 w1 = *(const float4*)(xp1 + oi + 4);
            a0.x += z0.x + y0.x + w0.x;
            a0.y += z0.y + y0.y + w0.y;
            a0.z += z0.z + y0.z + w0.z;
            a0.w += z0.w + y0.w + w0.w;
            a1.x += z1.x + y1.x + w1.x;
            a1.y += z1.y + y1.y + w1.y;
            a1.z += z1.z + y1.z + w1.z;
            a1.w += z1.w + y1.w + w1.w;
        }
        *(float4*)(x_out + oi) = a0;
        *(float4*)(x_out + oi + 4) = a1;
    }
}

// ---------------- Rating GEMM: (batch x 64) * (64 x n_items), fp32 ----------------

#define BM 128
#define BN 128
#define TM 8
#define TN 8
#define KB 32
#define PAD 4

__global__ __launch_bounds__(256) void rating_gemm_kernel(
        const float* __restrict__ acc, const int* __restrict__ users,
        float* __restrict__ out, int n_users, int n_items, int batch) {
    __shared__ __align__(16) float As[KB][BM + PAD];
    __shared__ __align__(16) float Bs[KB][BN + PAD];
    int m0 = blockIdx.y * BM;
    int n0 = blockIdx.x * BN;
    int tid = threadIdx.x;
    int tx = tid & 15, ty = tid >> 4;
    float c[TM][TN] = {};

    for (int k0 = 0; k0 < D; k0 += KB) {
        for (int f = tid; f < BM * (KB / 4); f += 256) {
            int m = f >> 3;
            int k4 = (f & 7) * 4;
            float4 a = make_float4(0.f, 0.f, 0.f, 0.f);
            int gm = m0 + m;
            if (gm < batch) {
                int uid = users[gm];
                a = *(const float4*)(acc + (size_t)uid * D + k0 + k4);
            }
            As[k4 + 0][m] = a.x; As[k4 + 1][m] = a.y;
            As[k4 + 2][m] = a.z; As[k4 + 3][m] = a.w;
        }
        for (int f = tid; f < BN * (KB / 4); f += 256) {
            int n = f >> 3;
            int k4 = (f & 7) * 4;
            float4 b = make_float4(0.f, 0.f, 0.f, 0.f);
            int gi = n0 + n;
            if (gi < n_items) {
                b = *(const float4*)(acc + (size_t)(n_users + gi) * D + k0 + k4);
            }
            Bs[k4 + 0][n] = b.x; Bs[k4 + 1][n] = b.y;
            Bs[k4 + 2][n] = b.z; Bs[k4 + 3][n] = b.w;
        }
        __syncthreads();
        #pragma unroll
        for (int k = 0; k < KB; ++k) {
            float a[TM], b[TN];
            float4 t;
            t = *(const float4*)&As[k][ty * TM];     a[0] = t.x; a[1] = t.y; a[2] = t.z; a[3] = t.w;
            t = *(const float4*)&As[k][ty * TM + 4]; a[4] = t.x; a[5] = t.y; a[6] = t.z; a[7] = t.w;
            t = *(const float4*)&Bs[k][tx * TN];     b[0] = t.x; b[1] = t.y; b[2] = t.z; b[3] = t.w;
            t = *(const float4*)&Bs[k][tx * TN + 4]; b[4] = t.x; b[5] = t.y; b[6] = t.z; b[7] = t.w;
            #pragma unroll
            for (int i = 0; i < TM; ++i)
                #pragma unroll
                for (int j = 0; j < TN; ++j)
                    c[i][j] = fmaf(a[i], b[j], c[i][j]);
        }
        __syncthreads();
    }

    const float S = 1.0f / 16.0f;  // (acc/4)·(acc/4)
    for (int i = 0; i < TM; ++i) {
        int m = m0 + ty * TM + i;
        if (m >= batch) break;
        float* row = out + (size_t)m * n_items;
        for (int j = 0; j < TN; j += 4) {
            int n = n0 + tx * TN + j;
            if (n + 4 <= n_items) {
                float4 v;
                v.x = c[i][j + 0] * S; v.y = c[i][j + 1] * S;
                v.z = c[i][j + 2] * S; v.w = c[i][j + 3] * S;
                *(float4*)(row + n) = v;
            } else {
                for (int u = 0; u < 4; ++u)
                    if (n + u < n_items) row[n + u] = c[i][j + u] * S;
            }
        }
    }
}

// ---------------- launcher ----------------

extern "C" void kernel_launch(void* const* d_in, const int* in_sizes, int n_in,
                              void* d_out, int out_size, void* d_ws, size_t ws_size,
                              hipStream_t stream) {
    const float* user_emb = (const float*)d_in[0];
    const float* item_emb = (const float*)d_in[1];
    const float* edge_val = (const float*)d_in[2];
    const int*   edge_src = (const int*)d_in[3];
    const int*   edge_dst = (const int*)d_in[4];
    const int*   users    = (const int*)d_in[5];

    const int n_users = in_sizes[0] / D;   // 100000
    const int n_items = in_sizes[1] / D;   // 50000
    const int nnz     = in_sizes[2];       // 4000000
    const int batch   = in_sizes[5];       // 2048
    const int n_nodes = n_users + n_items; // 150000

    // workspace carve-out (~148 MB)
    char* w = (char*)d_ws;
    size_t off = 0;
    auto alloc = [&](size_t bytes) -> void* {
        void* p = w + off;
        off += (bytes + 255) & ~(size_t)255;
        return p;
    };
    float* acc      = (float*)alloc((size_t)n_nodes * D * 4);
    float* xA       = (float*)alloc((size_t)n_nodes * D * 4);
    float* xB       = (float*)alloc((size_t)n_nodes * D * 4);
    int*   counts   = (int*)alloc((size_t)n_nodes * 4);
    int*   offs     = (int*)alloc((size_t)(n_nodes + 1) * 4);
    int*   partials = (int*)alloc((size_t)SCAN_BS * 4);
    int*   cursor   = (int*)alloc((size_t)n_nodes * 4);
    int2*  csr      = (int2*)alloc((size_t)nnz * 8);
    (void)ws_size; (void)n_in; (void)out_size;

    // CSR by dst
    hipMemsetAsync(counts, 0, (size_t)n_nodes * 4, stream);
    count_deg_kernel<<<(nnz + 255) / 256, 256, 0, stream>>>(edge_dst, counts, nnz);
    int nb = (n_nodes + SCAN_BS - 1) / SCAN_BS;
    scan_blocks_kernel<<<nb, SCAN_BS, 0, stream>>>(counts, offs, partials, n_nodes);
    scan_partials_kernel<<<1, SCAN_BS, 0, stream>>>(partials, nb);
    add_base_kernel<<<nb, SCAN_BS, 0, stream>>>(offs, partials, n_nodes, nnz);
    hipMemcpyAsync(cursor, offs, (size_t)n_nodes * 4, hipMemcpyDeviceToDevice, stream);
    fill_csr_kernel<<<2048, 256, 0, stream>>>(edge_src, edge_dst, edge_val,
                                              cursor, csr, nnz, n_nodes);

    // 3 SpMM layers; acc finalized inside layer 3 (acc = emb + x1 + x2 + x3)
    int spmm_blocks = (n_nodes + 3) / 4;  // 4 waves per 256-thread block
    spmm_kernel<true, false><<<spmm_blocks, 256, 0, stream>>>(
        offs, csr, nullptr, user_emb, item_emb, nullptr, nullptr, xA, n_nodes, n_users);
    spmm_kernel<false, false><<<spmm_blocks, 256, 0, stream>>>(
        offs, csr, xA, nullptr, nullptr, nullptr, nullptr, xB, n_nodes, n_users);
    spmm_kernel<false, true><<<spmm_blocks, 256, 0, stream>>>(
        offs, csr, xB, user_emb, item_emb, xA, xB, acc, n_nodes, n_users);

    // rating = users_emb @ items^T / 16
    dim3 ggrid((n_items + BN - 1) / BN, (batch + BM - 1) / BM);
    rating_gemm_kernel<<<ggrid, 256, 0, stream>>>(acc, users, (float*)d_out,
                                                  n_users, n_items, batch);
}

// Round 7
// 1292.563 us; speedup vs baseline: 1.3493x; 1.0731x over previous
//
#include <hip/hip_runtime.h>

#define D 64
#define SCAN_BS 1024

// ---------------- CSR build ----------------

__global__ void count_deg_kernel(const int* __restrict__ dst, int* __restrict__ counts, int nnz) {
    int e = blockIdx.x * blockDim.x + threadIdx.x;
    if (e < nnz) atomicAdd(&counts[dst[e]], 1);
}

__global__ void scan_blocks_kernel(const int* __restrict__ counts, int* __restrict__ offs,
                                   int* __restrict__ partials, int n) {
    __shared__ int sh[SCAN_BS];
    int tid = threadIdx.x;
    int i = blockIdx.x * SCAN_BS + tid;
    int v = (i < n) ? counts[i] : 0;
    sh[tid] = v;
    __syncthreads();
    for (int ofs = 1; ofs < SCAN_BS; ofs <<= 1) {
        int t = (tid >= ofs) ? sh[tid - ofs] : 0;
        __syncthreads();
        sh[tid] += t;
        __syncthreads();
    }
    if (i < n) offs[i] = sh[tid] - v;  // exclusive within block
    if (tid == SCAN_BS - 1) partials[blockIdx.x] = sh[tid];
}

__global__ void scan_partials_kernel(int* partials, int nb) {
    __shared__ int sh[SCAN_BS];
    int tid = threadIdx.x;
    int v = (tid < nb) ? partials[tid] : 0;
    sh[tid] = v;
    __syncthreads();
    for (int ofs = 1; ofs < SCAN_BS; ofs <<= 1) {
        int t = (tid >= ofs) ? sh[tid - ofs] : 0;
        __syncthreads();
        sh[tid] += t;
        __syncthreads();
    }
    if (tid < nb) partials[tid] = sh[tid] - v;  // exclusive
}

__global__ void add_base_kernel(int* __restrict__ offs, const int* __restrict__ partials,
                                int n, int nnz) {
    int i = blockIdx.x * SCAN_BS + threadIdx.x;
    if (i < n) offs[i] += partials[blockIdx.x];
    if (blockIdx.x == 0 && threadIdx.x == 0) offs[n] = nnz;
}

// fill: 8 dst-range groups keyed by blockIdx&7 (XCD round-robin heuristic).
// Each group's CSR region is ~4 MB -> single-L2 resident -> scattered 8B
// stores to the same 64B line merge before writeback.
__global__ __launch_bounds__(256) void fill_csr_kernel(
        const int* __restrict__ src, const int* __restrict__ dst,
        const float* __restrict__ val, int* __restrict__ cursor,
        int2* __restrict__ csr, int nnz, int n_nodes) {
    int grp = blockIdx.x & 7;
    int blk = blockIdx.x >> 3;
    int nblk = (int)(gridDim.x >> 3);
    int lo = (int)(((long long)n_nodes * grp) >> 3);
    int hi = (int)(((long long)n_nodes * (grp + 1)) >> 3);
    int per = (nnz + nblk - 1) / nblk;
    int e_beg = blk * per;
    int e_end = min(nnz, e_beg + per);
    for (int e = e_beg + (int)threadIdx.x; e < e_end; e += 256) {
        int d = __builtin_nontemporal_load(&dst[e]);
        if (d >= lo && d < hi) {
            int p = atomicAdd(&cursor[d], 1);
            int2 pk = make_int2(__float_as_int(__builtin_nontemporal_load(&val[e])),
                                __builtin_nontemporal_load(&src[e]));
            csr[p] = pk;
        }
    }
}

// ---------------- SpMM: one wave per dst node ----------------
// 8 lane-groups of 8; group g handles edge j+g via 2x float4 row reads,
// 2-stage software pipeline across trips, 3-step shfl_xor reduce.
// MODE 0: first layer (gather from emb), full node range.
// MODE 1: middle layer (gather from x_in), full node range.
// MODE 2: last layer, RESTRICTED to {sampled users} U {all items} —
//         the only acc rows the rating GEMM reads. ~1.39M of 4M edges.
//         Fuses acc finalize: acc = emb + x1 + x2 + spmm_sum.
//         Duplicate user ids -> byte-identical writes (benign race).

template <int MODE>
__global__ __launch_bounds__(256) void spmm_kernel(
        const int* __restrict__ offs, const int2* __restrict__ csr,
        const float* __restrict__ x_in,
        const float* __restrict__ user_emb, const float* __restrict__ item_emb,
        const float* __restrict__ xp0, const float* __restrict__ xp1,
        const int* __restrict__ users, int batch,
        float* __restrict__ x_out,
        int n_waves, int n_users) {
    int widx = (int)((blockIdx.x * blockDim.x + threadIdx.x) >> 6);
    if (widx >= n_waves) return;
    int node;
    if (MODE == 2)
        node = (widx < batch) ? users[widx] : n_users + (widx - batch);
    else
        node = widx;
    int lane = threadIdx.x & 63;
    int g = lane >> 3;       // edge sub-group 0..7
    int sl = lane & 7;       // feature-octet index (floats [sl*8, sl*8+8))
    int e0 = offs[node], e1 = offs[node + 1];
    float4 a0 = make_float4(0.f, 0.f, 0.f, 0.f);
    float4 a1 = make_float4(0.f, 0.f, 0.f, 0.f);

    for (int base = e0; base < e1; base += 64) {
        int e = base + lane;
        int2 pe = make_int2(0, 0);               // val=0.0f, src=0 for OOB lanes
        if (e < e1) pe = csr[e];                 // coalesced 512B chunk load
        int cnt = min(64, e1 - base);
        float pv = __int_as_float(pe.x);
        int   ps = pe.y;

        // prologue: issue loads for trip j=0
        float vc; float4 c0, c1;
        {
            int jj = g;                          // <= 7
            vc = __shfl(pv, jj);                 // 0.0 when jj >= cnt -> FMA no-op
            int sj = __shfl(ps, jj);             // 0 when jj >= cnt -> safe addr
            const float* rp;
            if (MODE == 0)
                rp = (sj < n_users) ? (user_emb + (size_t)sj * D)
                                    : (item_emb + (size_t)(sj - n_users) * D);
            else
                rp = x_in + (size_t)sj * D;
            const float4* rq = (const float4*)rp;
            c0 = rq[sl * 2];
            c1 = rq[sl * 2 + 1];
        }
        for (int j = 0; j < cnt; j += 8) {
            float vn = 0.f;
            float4 n0 = make_float4(0.f, 0.f, 0.f, 0.f);
            float4 n1 = make_float4(0.f, 0.f, 0.f, 0.f);
            if (j + 8 < cnt) {                   // wave-uniform; jj <= 63 guaranteed
                int jj = j + 8 + g;
                vn = __shfl(pv, jj);
                int sj = __shfl(ps, jj);
                const float* rp;
                if (MODE == 0)
                    rp = (sj < n_users) ? (user_emb + (size_t)sj * D)
                                        : (item_emb + (size_t)(sj - n_users) * D);
                else
                    rp = x_in + (size_t)sj * D;
                const float4* rq = (const float4*)rp;
                n0 = rq[sl * 2];                 // issued before current FMAs ->
                n1 = rq[sl * 2 + 1];             // up to 4 gathers in flight
            }
            a0.x = fmaf(vc, c0.x, a0.x);
            a0.y = fmaf(vc, c0.y, a0.y);
            a0.z = fmaf(vc, c0.z, a0.z);
            a0.w = fmaf(vc, c0.w, a0.w);
            a1.x = fmaf(vc, c1.x, a1.x);
            a1.y = fmaf(vc, c1.y, a1.y);
            a1.z = fmaf(vc, c1.z, a1.z);
            a1.w = fmaf(vc, c1.w, a1.w);
            vc = vn; c0 = n0; c1 = n1;
        }
    }

    // reduce the 8 edge-groups: lanes {g*8+sl} -> xor over g bits (8,16,32)
    a0.x += __shfl_xor(a0.x, 8);  a0.x += __shfl_xor(a0.x, 16); a0.x += __shfl_xor(a0.x, 32);
    a0.y += __shfl_xor(a0.y, 8);  a0.y += __shfl_xor(a0.y, 16); a0.y += __shfl_xor(a0.y, 32);
    a0.z += __shfl_xor(a0.z, 8);  a0.z += __shfl_xor(a0.z, 16); a0.z += __shfl_xor(a0.z, 32);
    a0.w += __shfl_xor(a0.w, 8);  a0.w += __shfl_xor(a0.w, 16); a0.w += __shfl_xor(a0.w, 32);
    a1.x += __shfl_xor(a1.x, 8);  a1.x += __shfl_xor(a1.x, 16); a1.x += __shfl_xor(a1.x, 32);
    a1.y += __shfl_xor(a1.y, 8);  a1.y += __shfl_xor(a1.y, 16); a1.y += __shfl_xor(a1.y, 32);
    a1.z += __shfl_xor(a1.z, 8);  a1.z += __shfl_xor(a1.z, 16); a1.z += __shfl_xor(a1.z, 32);
    a1.w += __shfl_xor(a1.w, 8);  a1.w += __shfl_xor(a1.w, 16); a1.w += __shfl_xor(a1.w, 32);

    if (lane < 8) {
        size_t oi = (size_t)node * D + (size_t)sl * 8;
        if (MODE == 2) {
            // acc = x0(own emb) + x1 + x2 + spmm_sum   (all coalesced own-row reads)
            const float* ep = (node < n_users) ? (user_emb + (size_t)node * D)
                                               : (item_emb + (size_t)(node - n_users) * D);
            float4 z0 = ((const float4*)ep)[sl * 2];
            float4 z1 = ((const float4*)ep)[sl * 2 + 1];
            float4 y0 = *(const float4*)(xp0 + oi);
            float4 y1 = *(const float4*)(xp0 + oi + 4);
            float4 w0 = *(const float4*)(xp1 + oi);
            float4 w1 = *(const float4*)(xp1 + oi + 4);
            a0.x += z0.x + y0.x + w0.x;
            a0.y += z0.y + y0.y + w0.y;
            a0.z += z0.z + y0.z + w0.z;
            a0.w += z0.w + y0.w + w0.w;
            a1.x += z1.x + y1.x + w1.x;
            a1.y += z1.y + y1.y + w1.y;
            a1.z += z1.z + y1.z + w1.z;
            a1.w += z1.w + y1.w + w1.w;
        }
        *(float4*)(x_out + oi) = a0;
        *(float4*)(x_out + oi + 4) = a1;
    }
}

// ---------------- Rating GEMM: (batch x 64) * (64 x n_items), fp32 ----------------

#define BM 128
#define BN 128
#define TM 8
#define TN 8
#define KB 32
#define PAD 4

__global__ __launch_bounds__(256) void rating_gemm_kernel(
        const float* __restrict__ acc, const int* __restrict__ users,
        float* __restrict__ out, int n_users, int n_items, int batch) {
    __shared__ __align__(16) float As[KB][BM + PAD];
    __shared__ __align__(16) float Bs[KB][BN + PAD];
    int m0 = blockIdx.y * BM;
    int n0 = blockIdx.x * BN;
    int tid = threadIdx.x;
    int tx = tid & 15, ty = tid >> 4;
    float c[TM][TN] = {};

    for (int k0 = 0; k0 < D; k0 += KB) {
        for (int f = tid; f < BM * (KB / 4); f += 256) {
            int m = f >> 3;
            int k4 = (f & 7) * 4;
            float4 a = make_float4(0.f, 0.f, 0.f, 0.f);
            int gm = m0 + m;
            if (gm < batch) {
                int uid = users[gm];
                a = *(const float4*)(acc + (size_t)uid * D + k0 + k4);
            }
            As[k4 + 0][m] = a.x; As[k4 + 1][m] = a.y;
            As[k4 + 2][m] = a.z; As[k4 + 3][m] = a.w;
        }
        for (int f = tid; f < BN * (KB / 4); f += 256) {
            int n = f >> 3;
            int k4 = (f & 7) * 4;
            float4 b = make_float4(0.f, 0.f, 0.f, 0.f);
            int gi = n0 + n;
            if (gi < n_items) {
                b = *(const float4*)(acc + (size_t)(n_users + gi) * D + k0 + k4);
            }
            Bs[k4 + 0][n] = b.x; Bs[k4 + 1][n] = b.y;
            Bs[k4 + 2][n] = b.z; Bs[k4 + 3][n] = b.w;
        }
        __syncthreads();
        #pragma unroll
        for (int k = 0; k < KB; ++k) {
            float a[TM], b[TN];
            float4 t;
            t = *(const float4*)&As[k][ty * TM];     a[0] = t.x; a[1] = t.y; a[2] = t.z; a[3] = t.w;
            t = *(const float4*)&As[k][ty * TM + 4]; a[4] = t.x; a[5] = t.y; a[6] = t.z; a[7] = t.w;
            t = *(const float4*)&Bs[k][tx * TN];     b[0] = t.x; b[1] = t.y; b[2] = t.z; b[3] = t.w;
            t = *(const float4*)&Bs[k][tx * TN + 4]; b[4] = t.x; b[5] = t.y; b[6] = t.z; b[7] = t.w;
            #pragma unroll
            for (int i = 0; i < TM; ++i)
                #pragma unroll
                for (int j = 0; j < TN; ++j)
                    c[i][j] = fmaf(a[i], b[j], c[i][j]);
        }
        __syncthreads();
    }

    const float S = 1.0f / 16.0f;  // (acc/4)·(acc/4)
    for (int i = 0; i < TM; ++i) {
        int m = m0 + ty * TM + i;
        if (m >= batch) break;
        float* row = out + (size_t)m * n_items;
        for (int j = 0; j < TN; j += 4) {
            int n = n0 + tx * TN + j;
            if (n + 4 <= n_items) {
                float4 v;
                v.x = c[i][j + 0] * S; v.y = c[i][j + 1] * S;
                v.z = c[i][j + 2] * S; v.w = c[i][j + 3] * S;
                *(float4*)(row + n) = v;
            } else {
                for (int u = 0; u < 4; ++u)
                    if (n + u < n_items) row[n + u] = c[i][j + u] * S;
            }
        }
    }
}

// ---------------- launcher ----------------

extern "C" void kernel_launch(void* const* d_in, const int* in_sizes, int n_in,
                              void* d_out, int out_size, void* d_ws, size_t ws_size,
                              hipStream_t stream) {
    const float* user_emb = (const float*)d_in[0];
    const float* item_emb = (const float*)d_in[1];
    const float* edge_val = (const float*)d_in[2];
    const int*   edge_src = (const int*)d_in[3];
    const int*   edge_dst = (const int*)d_in[4];
    const int*   users    = (const int*)d_in[5];

    const int n_users = in_sizes[0] / D;   // 100000
    const int n_items = in_sizes[1] / D;   // 50000
    const int nnz     = in_sizes[2];       // 4000000
    const int batch   = in_sizes[5];       // 2048
    const int n_nodes = n_users + n_items; // 150000

    // workspace carve-out (~148 MB)
    char* w = (char*)d_ws;
    size_t off = 0;
    auto alloc = [&](size_t bytes) -> void* {
        void* p = w + off;
        off += (bytes + 255) & ~(size_t)255;
        return p;
    };
    float* acc      = (float*)alloc((size_t)n_nodes * D * 4);
    float* xA       = (float*)alloc((size_t)n_nodes * D * 4);
    float* xB       = (float*)alloc((size_t)n_nodes * D * 4);
    int*   counts   = (int*)alloc((size_t)n_nodes * 4);
    int*   offs     = (int*)alloc((size_t)(n_nodes + 1) * 4);
    int*   partials = (int*)alloc((size_t)SCAN_BS * 4);
    int*   cursor   = (int*)alloc((size_t)n_nodes * 4);
    int2*  csr      = (int2*)alloc((size_t)nnz * 8);
    (void)ws_size; (void)n_in; (void)out_size;

    // CSR by dst
    hipMemsetAsync(counts, 0, (size_t)n_nodes * 4, stream);
    count_deg_kernel<<<(nnz + 255) / 256, 256, 0, stream>>>(edge_dst, counts, nnz);
    int nb = (n_nodes + SCAN_BS - 1) / SCAN_BS;
    scan_blocks_kernel<<<nb, SCAN_BS, 0, stream>>>(counts, offs, partials, n_nodes);
    scan_partials_kernel<<<1, SCAN_BS, 0, stream>>>(partials, nb);
    add_base_kernel<<<nb, SCAN_BS, 0, stream>>>(offs, partials, n_nodes, nnz);
    hipMemcpyAsync(cursor, offs, (size_t)n_nodes * 4, hipMemcpyDeviceToDevice, stream);
    fill_csr_kernel<<<2048, 256, 0, stream>>>(edge_src, edge_dst, edge_val,
                                              cursor, csr, nnz, n_nodes);

    // layers 1-2: full node range (outputs feed all-node gathers)
    int full_blocks = (n_nodes + 3) / 4;  // 4 waves per 256-thread block
    spmm_kernel<0><<<full_blocks, 256, 0, stream>>>(
        offs, csr, nullptr, user_emb, item_emb, nullptr, nullptr, nullptr, 0,
        xA, n_nodes, n_users);
    spmm_kernel<1><<<full_blocks, 256, 0, stream>>>(
        offs, csr, xA, nullptr, nullptr, nullptr, nullptr, nullptr, 0,
        xB, n_nodes, n_users);

    // layer 3: ONLY rows the GEMM reads — batch users + all items (~1.39M of 4M edges)
    int n_waves3 = batch + n_items;
    int last_blocks = (n_waves3 + 3) / 4;
    spmm_kernel<2><<<last_blocks, 256, 0, stream>>>(
        offs, csr, xB, user_emb, item_emb, xA, xB, users, batch,
        acc, n_waves3, n_users);

    // rating = users_emb @ items^T / 16
    dim3 ggrid((n_items + BN - 1) / BN, (batch + BM - 1) / BM);
    rating_gemm_kernel<<<ggrid, 256, 0, stream>>>(acc, users, (float*)d_out,
                                                  n_users, n_items, batch);
}

// Round 8
// 1165.739 us; speedup vs baseline: 1.4961x; 1.1088x over previous
//
#include <hip/hip_runtime.h>
#include <hip/hip_fp16.h>

#define D 64
#define SCAN_BS 1024

// ---------------- CSR build ----------------

__global__ void count_deg_kernel(const int* __restrict__ dst, int* __restrict__ counts, int nnz) {
    int e = blockIdx.x * blockDim.x + threadIdx.x;
    if (e < nnz) atomicAdd(&counts[dst[e]], 1);
}

__global__ void scan_blocks_kernel(const int* __restrict__ counts, int* __restrict__ offs,
                                   int* __restrict__ partials, int n) {
    __shared__ int sh[SCAN_BS];
    int tid = threadIdx.x;
    int i = blockIdx.x * SCAN_BS + tid;
    int v = (i < n) ? counts[i] : 0;
    sh[tid] = v;
    __syncthreads();
    for (int ofs = 1; ofs < SCAN_BS; ofs <<= 1) {
        int t = (tid >= ofs) ? sh[tid - ofs] : 0;
        __syncthreads();
        sh[tid] += t;
        __syncthreads();
    }
    if (i < n) offs[i] = sh[tid] - v;  // exclusive within block
    if (tid == SCAN_BS - 1) partials[blockIdx.x] = sh[tid];
}

__global__ void scan_partials_kernel(int* partials, int nb) {
    __shared__ int sh[SCAN_BS];
    int tid = threadIdx.x;
    int v = (tid < nb) ? partials[tid] : 0;
    sh[tid] = v;
    __syncthreads();
    for (int ofs = 1; ofs < SCAN_BS; ofs <<= 1) {
        int t = (tid >= ofs) ? sh[tid - ofs] : 0;
        __syncthreads();
        sh[tid] += t;
        __syncthreads();
    }
    if (tid < nb) partials[tid] = sh[tid] - v;  // exclusive
}

__global__ void add_base_kernel(int* __restrict__ offs, const int* __restrict__ partials,
                                int n, int nnz) {
    int i = blockIdx.x * SCAN_BS + threadIdx.x;
    if (i < n) offs[i] += partials[blockIdx.x];
    if (blockIdx.x == 0 && threadIdx.x == 0) offs[n] = nnz;
}

// fill: 8 dst-range groups keyed by blockIdx&7 (XCD round-robin heuristic).
__global__ __launch_bounds__(256) void fill_csr_kernel(
        const int* __restrict__ src, const int* __restrict__ dst,
        const float* __restrict__ val, int* __restrict__ cursor,
        int2* __restrict__ csr, int nnz, int n_nodes) {
    int grp = blockIdx.x & 7;
    int blk = blockIdx.x >> 3;
    int nblk = (int)(gridDim.x >> 3);
    int lo = (int)(((long long)n_nodes * grp) >> 3);
    int hi = (int)(((long long)n_nodes * (grp + 1)) >> 3);
    int per = (nnz + nblk - 1) / nblk;
    int e_beg = blk * per;
    int e_end = min(nnz, e_beg + per);
    for (int e = e_beg + (int)threadIdx.x; e < e_end; e += 256) {
        int d = __builtin_nontemporal_load(&dst[e]);
        if (d >= lo && d < hi) {
            int p = atomicAdd(&cursor[d], 1);
            int2 pk = make_int2(__float_as_int(__builtin_nontemporal_load(&val[e])),
                                __builtin_nontemporal_load(&src[e]));
            csr[p] = pk;
        }
    }
}

// ---------------- fp16 mirror of concat(user_emb, item_emb) ----------------

__global__ __launch_bounds__(256) void cvt_emb_kernel(
        const float* __restrict__ ue, const float* __restrict__ ie,
        __half* __restrict__ out, int n_user_f, int n_total_f) {
    int i = (blockIdx.x * blockDim.x + threadIdx.x) * 4;
    if (i >= n_total_f) return;
    const float* s = (i < n_user_f) ? (ue + i) : (ie + (i - n_user_f));
    float4 v = *(const float4*)s;              // n_user_f multiple of 4 -> no straddle
    __half2 h0 = __floats2half2_rn(v.x, v.y);
    __half2 h1 = __floats2half2_rn(v.z, v.w);
    *(uint2*)(out + i) = make_uint2(*(unsigned*)&h0, *(unsigned*)&h1);
}

// ---------------- SpMM: one wave per dst node, fp16 gathers ----------------
// Row = 64 halves = 128 B. 8 lane-groups of 8: group g handles edge j+g,
// lane sl loads one uint4 (8 halves) -> 8 lanes cover the row. 2-stage
// pipeline across trips; edge_val stays fp32 (from csr). Accum fp32.
// !LAST: write fp16 mirror only (next layer gathers it).
// LAST:  restricted to {sampled users} U {all items}; fuses
//        acc = emb(fp32) + x1(fp16 own-row) + x2(fp16 own-row) + spmm_sum.

template <bool LAST>
__global__ __launch_bounds__(256) void spmm_h_kernel(
        const int* __restrict__ offs, const int2* __restrict__ csr,
        const __half* __restrict__ xh_in,
        __half* __restrict__ xh_out,
        const float* __restrict__ user_emb, const float* __restrict__ item_emb,
        const __half* __restrict__ x1h, const __half* __restrict__ x2h,
        const int* __restrict__ users, int batch,
        float* __restrict__ acc,
        int n_waves, int n_users) {
    int widx = (int)((blockIdx.x * blockDim.x + threadIdx.x) >> 6);
    if (widx >= n_waves) return;
    int node = LAST ? ((widx < batch) ? users[widx] : n_users + (widx - batch)) : widx;
    int lane = threadIdx.x & 63;
    int g = lane >> 3;       // edge sub-group 0..7
    int sl = lane & 7;       // feature-octet index (halves [sl*8, sl*8+8))
    int e0 = offs[node], e1 = offs[node + 1];
    float4 a0 = make_float4(0.f, 0.f, 0.f, 0.f);
    float4 a1 = make_float4(0.f, 0.f, 0.f, 0.f);

    for (int base = e0; base < e1; base += 64) {
        int e = base + lane;
        int2 pe = make_int2(0, 0);               // val=0.0f, src=0 for OOB lanes
        if (e < e1) pe = csr[e];                 // coalesced 512B chunk load
        int cnt = min(64, e1 - base);
        float pv = __int_as_float(pe.x);
        int   ps = pe.y;

        float vc; uint4 hc;
        {
            vc = __shfl(pv, g);                  // 0.0 when g >= cnt -> FMA no-op
            int sj = __shfl(ps, g);              // 0 when g >= cnt -> safe addr
            hc = ((const uint4*)(xh_in + (size_t)sj * D))[sl];  // 8 lanes x 16B = row
        }
        for (int j = 0; j < cnt; j += 8) {
            float vn = 0.f;
            uint4 hn = make_uint4(0, 0, 0, 0);
            if (j + 8 < cnt) {                   // wave-uniform; jj <= 63 guaranteed
                int jj = j + 8 + g;
                vn = __shfl(pv, jj);
                int sj = __shfl(ps, jj);
                hn = ((const uint4*)(xh_in + (size_t)sj * D))[sl];  // issued early
            }
            float2 f0 = __half22float2(*(__half2*)&hc.x);
            float2 f1 = __half22float2(*(__half2*)&hc.y);
            float2 f2 = __half22float2(*(__half2*)&hc.z);
            float2 f3 = __half22float2(*(__half2*)&hc.w);
            a0.x = fmaf(vc, f0.x, a0.x); a0.y = fmaf(vc, f0.y, a0.y);
            a0.z = fmaf(vc, f1.x, a0.z); a0.w = fmaf(vc, f1.y, a0.w);
            a1.x = fmaf(vc, f2.x, a1.x); a1.y = fmaf(vc, f2.y, a1.y);
            a1.z = fmaf(vc, f3.x, a1.z); a1.w = fmaf(vc, f3.y, a1.w);
            vc = vn; hc = hn;
        }
    }

    // reduce the 8 edge-groups: xor over g bits (8,16,32)
    a0.x += __shfl_xor(a0.x, 8);  a0.x += __shfl_xor(a0.x, 16); a0.x += __shfl_xor(a0.x, 32);
    a0.y += __shfl_xor(a0.y, 8);  a0.y += __shfl_xor(a0.y, 16); a0.y += __shfl_xor(a0.y, 32);
    a0.z += __shfl_xor(a0.z, 8);  a0.z += __shfl_xor(a0.z, 16); a0.z += __shfl_xor(a0.z, 32);
    a0.w += __shfl_xor(a0.w, 8);  a0.w += __shfl_xor(a0.w, 16); a0.w += __shfl_xor(a0.w, 32);
    a1.x += __shfl_xor(a1.x, 8);  a1.x += __shfl_xor(a1.x, 16); a1.x += __shfl_xor(a1.x, 32);
    a1.y += __shfl_xor(a1.y, 8);  a1.y += __shfl_xor(a1.y, 16); a1.y += __shfl_xor(a1.y, 32);
    a1.z += __shfl_xor(a1.z, 8);  a1.z += __shfl_xor(a1.z, 16); a1.z += __shfl_xor(a1.z, 32);
    a1.w += __shfl_xor(a1.w, 8);  a1.w += __shfl_xor(a1.w, 16); a1.w += __shfl_xor(a1.w, 32);

    if (lane < 8) {
        size_t oi = (size_t)node * D + (size_t)sl * 8;
        if (LAST) {
            const float* ep = (node < n_users) ? (user_emb + (size_t)node * D)
                                               : (item_emb + (size_t)(node - n_users) * D);
            float4 z0 = ((const float4*)ep)[sl * 2];
            float4 z1 = ((const float4*)ep)[sl * 2 + 1];
            uint4 ha = *(const uint4*)(x1h + oi);   // own-row, coalesced
            uint4 hb = *(const uint4*)(x2h + oi);
            float2 u0 = __half22float2(*(__half2*)&ha.x);
            float2 u1 = __half22float2(*(__half2*)&ha.y);
            float2 u2 = __half22float2(*(__half2*)&ha.z);
            float2 u3 = __half22float2(*(__half2*)&ha.w);
            float2 w0 = __half22float2(*(__half2*)&hb.x);
            float2 w1 = __half22float2(*(__half2*)&hb.y);
            float2 w2 = __half22float2(*(__half2*)&hb.z);
            float2 w3 = __half22float2(*(__half2*)&hb.w);
            a0.x += z0.x + u0.x + w0.x;
            a0.y += z0.y + u0.y + w0.y;
            a0.z += z0.z + u1.x + w1.x;
            a0.w += z0.w + u1.y + w1.y;
            a1.x += z1.x + u2.x + w2.x;
            a1.y += z1.y + u2.y + w2.y;
            a1.z += z1.z + u3.x + w3.x;
            a1.w += z1.w + u3.y + w3.y;
            *(float4*)(acc + oi) = a0;
            *(float4*)(acc + oi + 4) = a1;
        } else {
            __half2 p0 = __floats2half2_rn(a0.x, a0.y);
            __half2 p1 = __floats2half2_rn(a0.z, a0.w);
            __half2 p2 = __floats2half2_rn(a1.x, a1.y);
            __half2 p3 = __floats2half2_rn(a1.z, a1.w);
            *(uint4*)(xh_out + oi) = make_uint4(*(unsigned*)&p0, *(unsigned*)&p1,
                                                *(unsigned*)&p2, *(unsigned*)&p3);
        }
    }
}

// ---------------- Rating GEMM: (batch x 64) * (64 x n_items), fp32 ----------------

#define BM 128
#define BN 128
#define TM 8
#define TN 8
#define KB 32
#define PAD 4

__global__ __launch_bounds__(256) void rating_gemm_kernel(
        const float* __restrict__ acc, const int* __restrict__ users,
        float* __restrict__ out, int n_users, int n_items, int batch) {
    __shared__ __align__(16) float As[KB][BM + PAD];
    __shared__ __align__(16) float Bs[KB][BN + PAD];
    int m0 = blockIdx.y * BM;
    int n0 = blockIdx.x * BN;
    int tid = threadIdx.x;
    int tx = tid & 15, ty = tid >> 4;
    float c[TM][TN] = {};

    for (int k0 = 0; k0 < D; k0 += KB) {
        for (int f = tid; f < BM * (KB / 4); f += 256) {
            int m = f >> 3;
            int k4 = (f & 7) * 4;
            float4 a = make_float4(0.f, 0.f, 0.f, 0.f);
            int gm = m0 + m;
            if (gm < batch) {
                int uid = users[gm];
                a = *(const float4*)(acc + (size_t)uid * D + k0 + k4);
            }
            As[k4 + 0][m] = a.x; As[k4 + 1][m] = a.y;
            As[k4 + 2][m] = a.z; As[k4 + 3][m] = a.w;
        }
        for (int f = tid; f < BN * (KB / 4); f += 256) {
            int n = f >> 3;
            int k4 = (f & 7) * 4;
            float4 b = make_float4(0.f, 0.f, 0.f, 0.f);
            int gi = n0 + n;
            if (gi < n_items) {
                b = *(const float4*)(acc + (size_t)(n_users + gi) * D + k0 + k4);
            }
            Bs[k4 + 0][n] = b.x; Bs[k4 + 1][n] = b.y;
            Bs[k4 + 2][n] = b.z; Bs[k4 + 3][n] = b.w;
        }
        __syncthreads();
        #pragma unroll
        for (int k = 0; k < KB; ++k) {
            float a[TM], b[TN];
            float4 t;
            t = *(const float4*)&As[k][ty * TM];     a[0] = t.x; a[1] = t.y; a[2] = t.z; a[3] = t.w;
            t = *(const float4*)&As[k][ty * TM + 4]; a[4] = t.x; a[5] = t.y; a[6] = t.z; a[7] = t.w;
            t = *(const float4*)&Bs[k][tx * TN];     b[0] = t.x; b[1] = t.y; b[2] = t.z; b[3] = t.w;
            t = *(const float4*)&Bs[k][tx * TN + 4]; b[4] = t.x; b[5] = t.y; b[6] = t.z; b[7] = t.w;
            #pragma unroll
            for (int i = 0; i < TM; ++i)
                #pragma unroll
                for (int j = 0; j < TN; ++j)
                    c[i][j] = fmaf(a[i], b[j], c[i][j]);
        }
        __syncthreads();
    }

    const float S = 1.0f / 16.0f;  // (acc/4)·(acc/4)
    for (int i = 0; i < TM; ++i) {
        int m = m0 + ty * TM + i;
        if (m >= batch) break;
        float* row = out + (size_t)m * n_items;
        for (int j = 0; j < TN; j += 4) {
            int n = n0 + tx * TN + j;
            if (n + 4 <= n_items) {
                float4 v;
                v.x = c[i][j + 0] * S; v.y = c[i][j + 1] * S;
                v.z = c[i][j + 2] * S; v.w = c[i][j + 3] * S;
                *(float4*)(row + n) = v;
            } else {
                for (int u = 0; u < 4; ++u)
                    if (n + u < n_items) row[n + u] = c[i][j + u] * S;
            }
        }
    }
}

// ---------------- launcher ----------------

extern "C" void kernel_launch(void* const* d_in, const int* in_sizes, int n_in,
                              void* d_out, int out_size, void* d_ws, size_t ws_size,
                              hipStream_t stream) {
    const float* user_emb = (const float*)d_in[0];
    const float* item_emb = (const float*)d_in[1];
    const float* edge_val = (const float*)d_in[2];
    const int*   edge_src = (const int*)d_in[3];
    const int*   edge_dst = (const int*)d_in[4];
    const int*   users    = (const int*)d_in[5];

    const int n_users = in_sizes[0] / D;   // 100000
    const int n_items = in_sizes[1] / D;   // 50000
    const int nnz     = in_sizes[2];       // 4000000
    const int batch   = in_sizes[5];       // 2048
    const int n_nodes = n_users + n_items; // 150000

    // workspace carve-out (~130 MB)
    char* w = (char*)d_ws;
    size_t off = 0;
    auto alloc = [&](size_t bytes) -> void* {
        void* p = w + off;
        off += (bytes + 255) & ~(size_t)255;
        return p;
    };
    float*  acc      = (float*)alloc((size_t)n_nodes * D * 4);
    __half* embh     = (__half*)alloc((size_t)n_nodes * D * 2);
    __half* xAh      = (__half*)alloc((size_t)n_nodes * D * 2);
    __half* xBh      = (__half*)alloc((size_t)n_nodes * D * 2);
    int*    counts   = (int*)alloc((size_t)n_nodes * 4);
    int*    offs     = (int*)alloc((size_t)(n_nodes + 1) * 4);
    int*    partials = (int*)alloc((size_t)SCAN_BS * 4);
    int*    cursor   = (int*)alloc((size_t)n_nodes * 4);
    int2*   csr      = (int2*)alloc((size_t)nnz * 8);
    (void)ws_size; (void)n_in; (void)out_size;

    // fp16 mirror of concat(user_emb, item_emb) — independent of CSR build
    int n_total_f = n_nodes * D;
    cvt_emb_kernel<<<(n_total_f / 4 + 255) / 256, 256, 0, stream>>>(
        user_emb, item_emb, embh, n_users * D, n_total_f);

    // CSR by dst
    hipMemsetAsync(counts, 0, (size_t)n_nodes * 4, stream);
    count_deg_kernel<<<(nnz + 255) / 256, 256, 0, stream>>>(edge_dst, counts, nnz);
    int nb = (n_nodes + SCAN_BS - 1) / SCAN_BS;
    scan_blocks_kernel<<<nb, SCAN_BS, 0, stream>>>(counts, offs, partials, n_nodes);
    scan_partials_kernel<<<1, SCAN_BS, 0, stream>>>(partials, nb);
    add_base_kernel<<<nb, SCAN_BS, 0, stream>>>(offs, partials, n_nodes, nnz);
    hipMemcpyAsync(cursor, offs, (size_t)n_nodes * 4, hipMemcpyDeviceToDevice, stream);
    fill_csr_kernel<<<2048, 256, 0, stream>>>(edge_src, edge_dst, edge_val,
                                              cursor, csr, nnz, n_nodes);

    // layers 1-2: full node range, fp16 gathers, fp16 outputs
    int full_blocks = (n_nodes + 3) / 4;  // 4 waves per 256-thread block
    spmm_h_kernel<false><<<full_blocks, 256, 0, stream>>>(
        offs, csr, embh, xAh, nullptr, nullptr, nullptr, nullptr, nullptr, 0,
        nullptr, n_nodes, n_users);
    spmm_h_kernel<false><<<full_blocks, 256, 0, stream>>>(
        offs, csr, xAh, xBh, nullptr, nullptr, nullptr, nullptr, nullptr, 0,
        nullptr, n_nodes, n_users);

    // layer 3: only rows the GEMM reads — batch users + all items (~1.39M of 4M edges)
    int n_waves3 = batch + n_items;
    int last_blocks = (n_waves3 + 3) / 4;
    spmm_h_kernel<true><<<last_blocks, 256, 0, stream>>>(
        offs, csr, xBh, nullptr, user_emb, item_emb, xAh, xBh, users, batch,
        acc, n_waves3, n_users);

    // rating = users_emb @ items^T / 16
    dim3 ggrid((n_items + BN - 1) / BN, (batch + BM - 1) / BM);
    rating_gemm_kernel<<<ggrid, 256, 0, stream>>>(acc, users, (float*)d_out,
                                                  n_users, n_items, batch);
}